// Round 14
// baseline (4235.307 us; speedup 1.0000x reference)
//
#include <hip/hip_runtime.h>

// R14: U rows pinned in VGPRs (kills 5.6e8 LDS bank conflicts + per-step U fetch);
// designated-block chains (s=b%8, spread over XCDs) + LLC R-broadcast
// (kills the 22.9 MB/step V/U refetch). Trajectory bit-identical to R13/R12/R9.

#define T_STEPS 128
#define NE 8192
#define NI 2048
#define NTOT 10240
#define BATCHES 32
#define SLICES 8
#define NT 512
#define NWB 320
#define DECAYF 0.904837429523468017578125f   // f32(exp(f32(-0.1)))

__device__ unsigned g_masks[2][BATCHES][NWB];   // parity spike masks
__device__ float    g_R[2][BATCHES][96];        // parity combined currents
__device__ unsigned g_cnt[BATCHES * 16];        // mask-arrival counters
__device__ unsigned g_step[BATCHES * 16];       // R-ready flags (monotonic)

#define MAC4(acc, rv, uv)                                   \
    acc = __fadd_rn(acc, __fmul_rn((rv).x, (uv).x));        \
    acc = __fadd_rn(acc, __fmul_rn((rv).y, (uv).y));        \
    acc = __fadd_rn(acc, __fmul_rn((rv).z, (uv).z));        \
    acc = __fadd_rn(acc, __fmul_rn((rv).w, (uv).w));

__global__ __launch_bounds__(NT, 1)
void snn_v14(const float* __restrict__ ext,
             const float* __restrict__ U_ee, const float* __restrict__ V_ee,
             const float* __restrict__ U_ei, const float* __restrict__ V_ei,
             const float* __restrict__ U_ie, const float* __restrict__ V_ie,
             float* __restrict__ out)
{
    __shared__ float sR1[32], sR2[32], sR3[32];
    __shared__ unsigned mw[NWB], pc[NWB];
    __shared__ unsigned short sIdxE[NE + 48];
    __shared__ unsigned short sIdxI[NI + 48];
    __shared__ int sCe, sCi;

    const int tid = threadIdx.x;
    const int b = blockIdx.x / SLICES;
    const int s = blockIdx.x % SLICES;
    const bool desig = (s == (b & 7));   // one chain-runner per batch, XCD-spread

    // ---- pin this thread's U rows in registers (fixed all run) ----
    float4 uA0[8], uB0[8], uA1[8], uB1[8], uC[8];
    {
        const float4* a0p = (const float4*)(U_ee + ((size_t)s * 1024 + tid) * 32);
        const float4* b0p = (const float4*)(U_ie + ((size_t)s * 1024 + tid) * 32);
        const float4* a1p = (const float4*)(U_ee + ((size_t)s * 1024 + 512 + tid) * 32);
        const float4* b1p = (const float4*)(U_ie + ((size_t)s * 1024 + 512 + tid) * 32);
        #pragma unroll
        for (int q = 0; q < 8; ++q) {
            uA0[q] = a0p[q]; uB0[q] = b0p[q]; uA1[q] = a1p[q]; uB1[q] = b1p[q];
        }
        if (tid >= 256) {
            const float4* cp = (const float4*)(U_ei + ((size_t)s * 256 + (tid - 256)) * 32);
            #pragma unroll
            for (int q = 0; q < 8; ++q) uC[q] = cp[q];
        } else {
            #pragma unroll
            for (int q = 0; q < 8; ++q) uC[q] = make_float4(0.f, 0.f, 0.f, 0.f);
        }
    }
    if (tid < 32) { sR1[tid] = 0.f; sR2[tid] = 0.f; sR3[tid] = 0.f; }
    __syncthreads();

    float v0 = 0.f, v1 = 0.f, vi = 0.f;
    int a0 = 0, a1 = 0, ai = 0;
    unsigned* c1  = &g_cnt[b * 16];
    unsigned* stp = &g_step[b * 16];

    for (int t = 0; t < T_STEPS; ++t) {
        const int par = t & 1;
        unsigned* gm = &g_masks[par][b][0];

        // ================= Phase E (order identical to R9/R12/R13) =================
        bool sp0, sp1, spi = false;
        {
            const float* extb = ext + ((size_t)b * T_STEPS + t) * NE + (size_t)s * 1024;
            const float xe0 = extb[tid];
            const float xe1 = extb[512 + tid];
            float t1 = 0.f, t2 = 0.f;
            #pragma unroll
            for (int q = 0; q < 8; ++q) {
                const float4 r1 = *(const float4*)&sR1[4 * q];
                const float4 r3 = *(const float4*)&sR3[4 * q];
                MAC4(t1, r1, uA0[q])
                MAC4(t2, r3, uB0[q])
            }
            const float I0 = __fadd_rn(__fadd_rn(t1, t2), xe0);
            v0 = __fadd_rn(__fmul_rn(v0, DECAYF), I0);
            sp0 = (v0 >= 1.0f); a0 += sp0 ? 1 : 0; if (sp0) v0 = 0.f;

            t1 = 0.f; t2 = 0.f;
            #pragma unroll
            for (int q = 0; q < 8; ++q) {
                const float4 r1 = *(const float4*)&sR1[4 * q];
                const float4 r3 = *(const float4*)&sR3[4 * q];
                MAC4(t1, r1, uA1[q])
                MAC4(t2, r3, uB1[q])
            }
            const float I1 = __fadd_rn(__fadd_rn(t1, t2), xe1);
            v1 = __fadd_rn(__fmul_rn(v1, DECAYF), I1);
            sp1 = (v1 >= 1.0f); a1 += sp1 ? 1 : 0; if (sp1) v1 = 0.f;

            if (tid >= 256) {
                float t3 = 0.f;
                #pragma unroll
                for (int q = 0; q < 8; ++q) {
                    const float4 r2 = *(const float4*)&sR2[4 * q];
                    MAC4(t3, r2, uC[q])
                }
                vi = __fadd_rn(__fmul_rn(vi, DECAYF), t3);
                spi = (vi >= 1.0f); ai += spi ? 1 : 0; if (spi) vi = 0.f;
            }
        }
        if (t == T_STEPS - 1) break;

        // ================= publish slice masks to LLC =================
        {
            const int wv = tid >> 6;
            const unsigned long long bal0 = __ballot(sp0);
            if ((tid & 63) == 0)
                __hip_atomic_store(&gm[s*32 + 2*wv],     (unsigned)bal0,         __ATOMIC_RELAXED, __HIP_MEMORY_SCOPE_AGENT);
            if ((tid & 63) == 32)
                __hip_atomic_store(&gm[s*32 + 2*wv + 1], (unsigned)(bal0 >> 32), __ATOMIC_RELAXED, __HIP_MEMORY_SCOPE_AGENT);
            const unsigned long long bal1 = __ballot(sp1);
            if ((tid & 63) == 0)
                __hip_atomic_store(&gm[s*32 + 16 + 2*wv],     (unsigned)bal1,         __ATOMIC_RELAXED, __HIP_MEMORY_SCOPE_AGENT);
            if ((tid & 63) == 32)
                __hip_atomic_store(&gm[s*32 + 16 + 2*wv + 1], (unsigned)(bal1 >> 32), __ATOMIC_RELAXED, __HIP_MEMORY_SCOPE_AGENT);
            if (tid >= 256) {
                const unsigned long long bi2 = __ballot(spi);
                if ((tid & 63) == 0)
                    __hip_atomic_store(&gm[256 + s*8 + 2*(wv-4)],     (unsigned)bi2,         __ATOMIC_RELAXED, __HIP_MEMORY_SCOPE_AGENT);
                if ((tid & 63) == 32)
                    __hip_atomic_store(&gm[256 + s*8 + 2*(wv-4) + 1], (unsigned)(bi2 >> 32), __ATOMIC_RELAXED, __HIP_MEMORY_SCOPE_AGENT);
            }
        }
        asm volatile("s_waitcnt vmcnt(0)" ::: "memory");
        __syncthreads();
        if (tid == 0)
            __hip_atomic_fetch_add(c1, 1u, __ATOMIC_RELAXED, __HIP_MEMORY_SCOPE_AGENT);

        if (desig) {
            // ---- wait for all 8 slices' masks ----
            if (tid == 0) {
                const unsigned target = 8u * (unsigned)(t + 1);
                while (__hip_atomic_load(c1, __ATOMIC_RELAXED, __HIP_MEMORY_SCOPE_AGENT) < target)
                    __builtin_amdgcn_s_sleep(1);
            }
            __syncthreads();
            if (tid < NWB)
                mw[tid] = __hip_atomic_load(&gm[tid], __ATOMIC_RELAXED, __HIP_MEMORY_SCOPE_AGENT);
            __syncthreads();
            // ---- compaction (1:1 tid<->word; proven R12/R13) ----
            if (tid < NWB) pc[tid] = (unsigned)__popc(mw[tid]);
            __syncthreads();
            for (int d = 1; d < 256; d <<= 1) {
                unsigned add = 0u; bool act = false;
                if (tid < 256)      { if (tid >= d)       { add = pc[tid - d]; act = true; } }
                else if (tid < NWB) { if (tid - 256 >= d) { add = pc[tid - d]; act = true; } }
                __syncthreads();
                if (act) pc[tid] += add;
                __syncthreads();
            }
            if (tid == 0)  sCe = (int)pc[255];
            if (tid == 64) sCi = (int)pc[319];
            __syncthreads();
            if (tid < NWB) {
                unsigned m = mw[tid];
                int off = (int)pc[tid] - __popc(m);
                if (tid < 256) {
                    const unsigned nb = (unsigned)tid * 32u;
                    while (m) { const int bit = __ffs(m) - 1; m &= m - 1;
                        sIdxE[off++] = (unsigned short)(nb + (unsigned)bit); }
                } else {
                    const unsigned nb = (unsigned)(tid - 256) * 32u;
                    while (m) { const int bit = __ffs(m) - 1; m &= m - 1;
                        sIdxI[off++] = (unsigned short)(nb + (unsigned)bit); }
                }
            }
            if (tid >= 320 && tid < 368)      sIdxE[sCe + (tid - 320)] = 0;
            else if (tid >= 384 && tid < 432) sIdxI[sCi + (tid - 384)] = 0;
            __syncthreads();
            // ---- serial chains, 3-deep x16 pipeline (ascending order preserved) ----
            if (tid < 96) {
                const int tb = tid >> 5;
                const int r = tid & 31;
                const float* __restrict__ V = ((tb == 0) ? V_ee : (tb == 1) ? V_ei : V_ie) + r;
                const unsigned short* __restrict__ ip = (tb == 2) ? sIdxI : sIdxE;
                const int cnt2 = (tb == 2) ? sCi : sCe;
                const int full = cnt2 >> 4;
                const int tail = cnt2 & 15;
                float a = 0.f;
                float xa[16], xb[16], xc[16];
                #pragma unroll
                for (int u = 0; u < 16; ++u) xa[u] = V[(unsigned)ip[u] * 32u];
                #pragma unroll
                for (int u = 0; u < 16; ++u) xb[u] = V[(unsigned)ip[16 + u] * 32u];
                #pragma unroll
                for (int u = 0; u < 16; ++u) xc[u] = V[(unsigned)ip[32 + u] * 32u];
                int g = 0;
                for (; g + 3 <= full; g += 3) {
                    #pragma unroll
                    for (int u = 0; u < 16; ++u) a = __fadd_rn(a, xa[u]);
                    #pragma unroll
                    for (int u = 0; u < 16; ++u) xa[u] = V[(unsigned)ip[(g + 3) * 16 + u] * 32u];
                    #pragma unroll
                    for (int u = 0; u < 16; ++u) a = __fadd_rn(a, xb[u]);
                    #pragma unroll
                    for (int u = 0; u < 16; ++u) xb[u] = V[(unsigned)ip[(g + 4) * 16 + u] * 32u];
                    #pragma unroll
                    for (int u = 0; u < 16; ++u) a = __fadd_rn(a, xc[u]);
                    #pragma unroll
                    for (int u = 0; u < 16; ++u) xc[u] = V[(unsigned)ip[(g + 5) * 16 + u] * 32u];
                }
                const int rem = full - g;
                if (rem == 0) {
                    #pragma unroll
                    for (int u = 0; u < 16; ++u) if (u < tail) a = __fadd_rn(a, xa[u]);
                } else if (rem == 1) {
                    #pragma unroll
                    for (int u = 0; u < 16; ++u) a = __fadd_rn(a, xa[u]);
                    #pragma unroll
                    for (int u = 0; u < 16; ++u) if (u < tail) a = __fadd_rn(a, xb[u]);
                } else {
                    #pragma unroll
                    for (int u = 0; u < 16; ++u) a = __fadd_rn(a, xa[u]);
                    #pragma unroll
                    for (int u = 0; u < 16; ++u) a = __fadd_rn(a, xb[u]);
                    #pragma unroll
                    for (int u = 0; u < 16; ++u) if (u < tail) a = __fadd_rn(a, xc[u]);
                }
                ((tb == 0) ? sR1 : (tb == 1) ? sR2 : sR3)[r] = a;
                __hip_atomic_store(&g_R[par][b][tid], a, __ATOMIC_RELAXED, __HIP_MEMORY_SCOPE_AGENT);
            }
            asm volatile("s_waitcnt vmcnt(0)" ::: "memory");
            __syncthreads();
            if (tid == 0)
                __hip_atomic_store(stp, (unsigned)(t + 1), __ATOMIC_RELAXED, __HIP_MEMORY_SCOPE_AGENT);
        } else {
            // ---- wait for R, read it ----
            if (tid == 0) {
                while (__hip_atomic_load(stp, __ATOMIC_RELAXED, __HIP_MEMORY_SCOPE_AGENT) < (unsigned)(t + 1))
                    __builtin_amdgcn_s_sleep(1);
            }
            __syncthreads();
            if (tid < 96) {
                const float x = __hip_atomic_load(&g_R[par][b][tid], __ATOMIC_RELAXED, __HIP_MEMORY_SCOPE_AGENT);
                const int tb = tid >> 5;
                ((tb == 0) ? sR1 : (tb == 1) ? sR2 : sR3)[tid & 31] = x;
            }
            __syncthreads();
        }
    }

    // ================= outputs: spike counts [B][Ne+Ni] =================
    {
        float* ob = out + (size_t)b * NTOT;
        ob[(size_t)s * 1024 + tid]       = (float)a0;
        ob[(size_t)s * 1024 + 512 + tid] = (float)a1;
        if (tid >= 256) ob[NE + (size_t)s * 256 + (tid - 256)] = (float)ai;
    }
}

extern "C" void kernel_launch(void* const* d_in, const int* in_sizes, int n_in,
                              void* d_out, int out_size, void* d_ws, size_t ws_size,
                              hipStream_t stream) {
    (void)in_sizes; (void)n_in; (void)d_ws; (void)ws_size; (void)out_size;
    const float* ext  = (const float*)d_in[0];
    const float* U_ee = (const float*)d_in[1];
    const float* V_ee = (const float*)d_in[2];
    const float* U_ei = (const float*)d_in[3];
    const float* V_ei = (const float*)d_in[4];
    const float* U_ie = (const float*)d_in[5];
    const float* V_ie = (const float*)d_in[6];

    void* p = nullptr;
    hipGetSymbolAddress(&p, HIP_SYMBOL(g_cnt));
    hipMemsetAsync(p, 0, sizeof(unsigned) * BATCHES * 16, stream);
    hipGetSymbolAddress(&p, HIP_SYMBOL(g_step));
    hipMemsetAsync(p, 0, sizeof(unsigned) * BATCHES * 16, stream);

    snn_v14<<<dim3(BATCHES * SLICES), dim3(NT), 0, stream>>>(
        ext, U_ee, V_ee, U_ei, V_ei, U_ie, V_ie, (float*)d_out);
}